// Round 14
// baseline (705.021 us; speedup 1.0000x reference)
//
#include <hip/hip_runtime.h>
#include <hip/hip_bf16.h>
#include <math.h>
#include <stdint.h>

// HolomorphicEqProp: B=4096, D_IN=H=1024, D_OUT=256, steps=30.
// Round-23: R22 FAILED (nt-STORE pushed h past L2 -> partner reads paid
// MALL latency on the critical path; dur 490->567). Reverted. Same thrash
// theory, READ-side fix: NON-TEMPORAL LOADS on h-image reads. nt-read
// demotes each h line to evict-first AFTER its single use (still hits L2);
// producer stores stay normal (allocate in L2, partner hits them fast).
// h lines then die before displacing Wr -> Wr converges L2-resident.
// Exactly ONE change on the R21 kernel (490us steady): sweepT<NF,NTH>,
// nt-loads only for h-image sources (recurrence + output GEMM), plain
// loads for x; h stores back to R21's plain uint2.

#define EPSF 1e-12f

typedef short bf16x8 __attribute__((ext_vector_type(8)));
typedef float f32x4 __attribute__((ext_vector_type(4)));

struct Mods { float m[32]; };

__device__ __forceinline__ unsigned short f2bf(float f) {
  union { float f; unsigned u; } v; v.f = f;
  unsigned r = v.u + 0x7FFFu + ((v.u >> 16) & 1u);  // RNE
  return (unsigned short)(r >> 16);
}

// packed f32x2 -> bf16x2 (RNE), single VALU op
__device__ __forceinline__ unsigned cvt_pk_bf16(float lo, float hi) {
  unsigned r;
  asm("v_cvt_pk_bf16_f32 %0, %1, %2" : "=v"(r) : "v"(lo), "v"(hi));
  return r;
}

// tanh(x) = 1 - 2/(exp(2x)+1). Saturates exactly; abs err ~1e-7 << bf16 eps.
__device__ __forceinline__ float tanh_fast(float x) {
  float e = __expf(2.0f * x);
  float r = __builtin_amdgcn_rcpf(e + 1.0f);
  return fmaf(-2.0f, r, 1.0f);
}

__device__ __forceinline__ float block_reduce_sum(float x) {
#pragma unroll
  for (int o = 32; o > 0; o >>= 1) x += __shfl_down(x, o, 64);
  __shared__ float sm[8];
  int lane = threadIdx.x & 63, w = threadIdx.x >> 6;
  if (lane == 0) sm[w] = x;
  __syncthreads();
  float t = 0.f;
  if (threadIdx.x == 0) {
    int nw = (int)(blockDim.x >> 6);
    for (int i = 0; i < nw; ++i) t += sm[i];
  }
  return t;
}

// ---------------- fused spectral-norm setup (fp32, exact) ----------------

__global__ void spec_col3(const float* __restrict__ Wi, const float* __restrict__ Wr,
                          const float* __restrict__ Wo, const float* __restrict__ ui,
                          const float* __restrict__ ur, const float* __restrict__ uo,
                          float* __restrict__ v) {
  int z = blockIdx.z;
  const float* W = (z == 0) ? Wi : (z == 1) ? Wr : Wo;
  const float* u = (z == 0) ? ui : (z == 1) ? ur : uo;
  int M = (z == 2) ? 256 : 1024;
  int i0 = blockIdx.y * 64;
  if (i0 >= M) return;
  int j = blockIdx.x * blockDim.x + threadIdx.x;
  float acc = 0.f;
  for (int i = i0; i < i0 + 64; ++i)
    acc += W[(size_t)i * 1024 + j] * u[i];
  atomicAdd(&v[z * 1024 + j], acc);
}

// Fused norm+rowsq (R19-validated): blocks 0..2303 rowsq, 2304..2306 norms.
__global__ void reduce3(const float* __restrict__ Wi, const float* __restrict__ Wr,
                        const float* __restrict__ Wo, const float* __restrict__ v,
                        float* __restrict__ S) {
  int bid = blockIdx.x;
  if (bid >= 2304) {
    int z = bid - 2304;
    float acc = 0.f;
    for (int i = threadIdx.x; i < 1024; i += blockDim.x) {
      float x = v[z * 1024 + i];
      acc += x * x;
    }
    float t = block_reduce_sum(acc);
    if (threadIdx.x == 0) S[z] = t;
    return;
  }
  int z = (bid < 1024) ? 0 : (bid < 2048) ? 1 : 2;
  int row = bid - ((z == 0) ? 0 : (z == 1) ? 1024 : 2048);
  const float* W = (z == 0) ? Wi : (z == 1) ? Wr : Wo;
  const float* vv = v + z * 1024;
  float acc = 0.f;
  for (int j = threadIdx.x; j < 1024; j += blockDim.x)
    acc += W[(size_t)row * 1024 + j] * vv[j];
  float r = block_reduce_sum(acc);
  if (threadIdx.x == 0) atomicAdd(&S[3 + z], r * r);
}

__device__ __forceinline__ ushort4 cvt4e(float4 w, float s) {
  ushort4 r;
  r.x = f2bf(w.x * s); r.y = f2bf(w.y * s); r.z = f2bf(w.z * s); r.w = f2bf(w.w * s);
  return r;
}

// sigma^-1 (exact spec_finalize math, inlined; R19-validated)
__device__ __forceinline__ float inv_sigma(float nvsq, float wv2) {
  float nv = sqrtf(nvsq);
  float inv = 1.f / (nv + EPSF);
  float u2sq = wv2 * inv * inv;
  float nu = sqrtf(u2sq);
  float sigma = u2sq / (nu + EPSF);
  return 1.f / sigma;
}

// Tiled-output conversion (R20-validated, byte-identical).
__global__ void cvt_all(const float4* __restrict__ Wi, const float4* __restrict__ Wr,
                        const float4* __restrict__ Wo, const float4* __restrict__ x,
                        const float* __restrict__ S,
                        ushort4* __restrict__ oWi, ushort4* __restrict__ oWr,
                        ushort4* __restrict__ oWo, ushort4* __restrict__ ox) {
  float s6 = inv_sigma(S[0], S[3]);
  float s7 = inv_sigma(S[1], S[4]);
  float s8 = inv_sigma(S[2], S[5]);
  int stride = gridDim.x * blockDim.x;
  int t0 = blockIdx.x * blockDim.x + threadIdx.x;
  for (int i = t0; i < 262144; i += stride) {  // Wi: 1024 rows
    int n = i >> 8, ku = i & 255;
    int kc = ku >> 3, quad = (ku >> 1) & 3, j4 = ku & 1;
    oWi[(((n >> 4) * 32 + kc) * 64 + (n & 15) + 16 * quad) * 2 + j4] = cvt4e(Wi[i], s6);
  }
  for (int i = t0; i < 262144; i += stride) {  // Wr: 1024 rows
    int n = i >> 8, ku = i & 255;
    int kc = ku >> 3, quad = (ku >> 1) & 3, j4 = ku & 1;
    oWr[(((n >> 4) * 32 + kc) * 64 + (n & 15) + 16 * quad) * 2 + j4] = cvt4e(Wr[i], s7);
  }
  for (int i = t0; i < 65536; i += stride) {   // Wo: 256 rows
    int n = i >> 8, ku = i & 255;
    int kc = ku >> 3, quad = (ku >> 1) & 3, j4 = ku & 1;
    oWo[(((n >> 4) * 32 + kc) * 64 + (n & 15) + 16 * quad) * 2 + j4] = cvt4e(Wo[i], s8);
  }
  for (int i = t0; i < 1048576; i += stride) { // x: 4096 rows, block-tiled
    int m = i >> 8, ku = i & 255;
    int kc = ku >> 3, quad = (ku >> 1) & 3, j4 = ku & 1;
    ox[(size_t)(m >> 5) * 8192 +
       ((((m >> 4) & 1) * 32 + kc) * 64 + (m & 15) + 16 * quad) * 2 + j4] =
        cvt4e(x[i], 1.0f);
  }
}

// ---------------- fused streaming RNN (pair-split, no LDS) ---------------

// K-sweep (R20-validated shape): B-operand h frags (2 mf) from hsrc,
// A-operand W frags (NF) streamed from global tiled weights. 4-set modulo
// schedule, lead ~3 sets. NTH: non-temporal h loads (evict-first demotion
// after the single per-step use; still L2-allocating/hitting) — used when
// hsrc is an h exchange image, NOT for x. All indices compile-time (#20).
template <int NF, bool NTH>
__device__ __forceinline__ void sweepT(const unsigned short* hsrc,
                                       const unsigned short* __restrict__ Wsrc,
                                       int lx, f32x4 acc[2][NF]) {
  bf16x8 hf[4][2], wf[4][NF];
#define LOADSET(S, KC)                                                      \
  {                                                                         \
    int kq = (KC) & 31;                                                     \
    if (NTH) {                                                              \
      hf[S][0] = __builtin_nontemporal_load(                                \
          (const bf16x8*)(hsrc + kq * 512 + lx));                           \
      hf[S][1] = __builtin_nontemporal_load(                                \
          (const bf16x8*)(hsrc + (32 + kq) * 512 + lx));                    \
    } else {                                                                \
      hf[S][0] = *(const bf16x8*)(hsrc + kq * 512 + lx);                    \
      hf[S][1] = *(const bf16x8*)(hsrc + (32 + kq) * 512 + lx);             \
    }                                                                       \
    _Pragma("unroll")                                                       \
    for (int nf = 0; nf < NF; ++nf)                                         \
      wf[S][nf] = *(const bf16x8*)(Wsrc + (nf * 32 + kq) * 512 + lx);       \
  }
  LOADSET(0, 0) LOADSET(1, 1) LOADSET(2, 2) LOADSET(3, 3)
#pragma unroll 1
  for (int kc = 0; kc < 32; kc += 4) {
#define STEP(S)                                                             \
    {                                                                       \
      __builtin_amdgcn_s_setprio(1);                                        \
      _Pragma("unroll")                                                     \
      for (int nf = 0; nf < NF; ++nf) {                                     \
        acc[0][nf] = __builtin_amdgcn_mfma_f32_16x16x32_bf16(               \
            wf[S][nf], hf[S][0], acc[0][nf], 0, 0, 0);                      \
        acc[1][nf] = __builtin_amdgcn_mfma_f32_16x16x32_bf16(               \
            wf[S][nf], hf[S][1], acc[1][nf], 0, 0, 0);                      \
      }                                                                     \
      __builtin_amdgcn_s_setprio(0);                                        \
      LOADSET(S, kc + S + 4)                                                \
    }
    STEP(0) STEP(1) STEP(2) STEP(3)
#undef STEP
  }
#undef LOADSET
}

// 256 blocks x 512 threads (8 waves = 2/SIMD). bid = s*128 + p:
// pair p (batch rows [p*32,+32)), half s (h-cols [s*512,+512)).
// Round-robin => XCD(bid) = bid&7 = p&7 for both halves (runtime-checked).
// h: global tiled images himg[p][parity] (64KB each; full 1024 cols,
// halves written disjointly by the two blocks). Wave w: cols
// [s*512 + w*64, +64) for recurrence, [s*128 + w*16, +16) for output.
__global__ __launch_bounds__(512, 2) void rnn_all(
    const unsigned short* __restrict__ xT,   // tiled x (per 32-row block)
    const unsigned short* __restrict__ WiT,  // tiled Wi (scaled bf16)
    const unsigned short* __restrict__ WrT,  // tiled Wr
    const unsigned short* __restrict__ WoT,  // tiled Wo
    const float* __restrict__ b_in,
    const float* __restrict__ b_rec,
    const float* __restrict__ b_out,
    unsigned short* __restrict__ himg,       // 128 pairs x 2 x 32768 shorts
    unsigned* __restrict__ flags,            // (p*2+s)*16 u32 stride (64B)
    unsigned* __restrict__ xcds,             // p*2+s
    float* __restrict__ outF,
    Mods mods) {
  const int tid = threadIdx.x;
  const int w = tid >> 6, lane = tid & 63;
  const int lrow = lane & 15, quad = lane >> 4;
  const int lx = lane * 8;
  const int bid = (int)blockIdx.x;
  const int p = bid & 127, s = bid >> 7;
  const int m0 = p * 32;
  const int nfbase = s * 32 + w * 4;        // Wr/Wi frag-row base for wave
  unsigned short* img0 = himg + (size_t)p * 65536;
  unsigned short* img1 = img0 + 32768;
  unsigned* myflag = flags + (size_t)(p * 2 + s) * 16;
  unsigned* ptflag = flags + (size_t)(p * 2 + (1 - s)) * 16;
  const unsigned short* xb = xT + (size_t)p * 32768;

  unsigned myxcc = 0;
  if (tid == 0) {
    asm volatile("s_getreg_b32 %0, hwreg(HW_REG_XCC_ID)" : "=s"(myxcc));
    // RELEASE: xcd publish drained before any later flag is observable.
    __hip_atomic_store(xcds + (p * 2 + s), myxcc, __ATOMIC_RELEASE,
                       __HIP_MEMORY_SCOPE_AGENT);
  }

  // per-lane biases for this wave's 64 recurrence cols
  float4 brec4[4];
#pragma unroll
  for (int nf = 0; nf < 4; ++nf)
    brec4[nf] = *(const float4*)&b_rec[s * 512 + w * 64 + nf * 16 + quad * 4];

  // ---- xproj: xpr[mf][nf] = (x @ Wi^T + b_in) for own 512 cols ----
  f32x4 xpr[2][4];
  {
    f32x4 xa[2][4] = {};
    sweepT<4, false>(xb, WiT + (size_t)nfbase * 32 * 512, lx, xa);
#pragma unroll
    for (int nf = 0; nf < 4; ++nf) {
      float4 bin4 = *(const float4*)&b_in[s * 512 + w * 64 + nf * 16 + quad * 4];
#pragma unroll
      for (int mf = 0; mf < 2; ++mf) {
        xpr[mf][nf][0] = xa[mf][nf][0] + bin4.x;
        xpr[mf][nf][1] = xa[mf][nf][1] + bin4.y;
        xpr[mf][nf][2] = xa[mf][nf][2] + bin4.z;
        xpr[mf][nf][3] = xa[mf][nf][3] + bin4.w;
      }
    }
  }

  int fastv = 1;  // meaningful in tid0 only; decided at t==1

  // ---- t = 0..29: compute h(t) into img[t&1] (own kc range) ----
#pragma unroll 1
  for (int t = 0; t < 30; ++t) {
    f32x4 acc[2][4] = {};
    if (t) {
      if (tid == 0) {
        while (__hip_atomic_load(ptflag, __ATOMIC_RELAXED,
                                 __HIP_MEMORY_SCOPE_AGENT) < (unsigned)t)
          __builtin_amdgcn_s_sleep(2);
        if (t == 1) {
          unsigned px = __hip_atomic_load(xcds + (p * 2 + (1 - s)),
                                          __ATOMIC_RELAXED, __HIP_MEMORY_SCOPE_AGENT);
          fastv = ((px & 15u) == (myxcc & 15u)) ? 1 : 0;
        }
        if (fastv) {
          asm volatile("buffer_inv sc0" ::: "memory");  // L1 only; h in XCD L2
        } else {
          (void)__hip_atomic_load(ptflag, __ATOMIC_ACQUIRE, __HIP_MEMORY_SCOPE_AGENT);
        }
      }
      __syncthreads();  // partner h(t-1) visible to all waves
      sweepT<4, true>((t & 1) ? img0 : img1, WrT + (size_t)nfbase * 32 * 512, lx, acc);
    }
    const float mod = mods.m[t];
    unsigned short* dst = (t & 1) ? img1 : img0;
#pragma unroll
    for (int nf = 0; nf < 4; ++nf) {
      // write own h as next step's B-frag (R20-validated mapping, kc
      // rebased to the pair image): ncol = s*512 + w*64 + nf*16 + quad*4+r
      const int kcp = s * 16 + w * 2 + (nf >> 1);
      const int lanep = lrow + 16 * (((nf & 1) * 2 + (quad >> 1)));
#pragma unroll
      for (int mf = 0; mf < 2; ++mf) {
        float h0 = tanh_fast(fmaf(acc[mf][nf][0] + brec4[nf].x, mod, xpr[mf][nf][0]));
        float h1 = tanh_fast(fmaf(acc[mf][nf][1] + brec4[nf].y, mod, xpr[mf][nf][1]));
        float h2 = tanh_fast(fmaf(acc[mf][nf][2] + brec4[nf].z, mod, xpr[mf][nf][2]));
        float h3 = tanh_fast(fmaf(acc[mf][nf][3] + brec4[nf].w, mod, xpr[mf][nf][3]));
        uint2 pk = {cvt_pk_bf16(h0, h1), cvt_pk_bf16(h2, h3)};
        *(uint2*)(dst + (mf * 32 + kcp) * 512 + lanep * 8 + (quad & 1) * 4) = pk;
      }
    }
    __syncthreads();  // all waves' h(t) stores drained to XCD L2
    if (tid == 0) {
      if (t == 0 || !fastv)  // t=0: release also orders the xcd publish path
        __hip_atomic_store(myflag, (unsigned)(t + 1), __ATOMIC_RELEASE,
                           __HIP_MEMORY_SCOPE_AGENT);
      else
        __hip_atomic_store(myflag, (unsigned)(t + 1), __ATOMIC_RELAXED,
                           __HIP_MEMORY_SCOPE_AGENT);
    }
  }

  // ---- fused output GEMM: out = h29 @ Wo^T + b_out (h29 = parity 1) ----
  if (tid == 0) {
    while (__hip_atomic_load(ptflag, __ATOMIC_RELAXED,
                             __HIP_MEMORY_SCOPE_AGENT) < 30u)
      __builtin_amdgcn_s_sleep(2);
    if (fastv) {
      asm volatile("buffer_inv sc0" ::: "memory");
    } else {
      (void)__hip_atomic_load(ptflag, __ATOMIC_ACQUIRE, __HIP_MEMORY_SCOPE_AGENT);
    }
  }
  __syncthreads();
  {
    f32x4 ao[2][1] = {};
    sweepT<1, true>(img1, WoT + (size_t)((s * 8 + w) * 32) * 512, lx, ao);
    float4 bo4 = *(const float4*)&b_out[s * 128 + w * 16 + quad * 4];
#pragma unroll
    for (int mf = 0; mf < 2; ++mf) {
      float4 o;
      o.x = ao[mf][0][0] + bo4.x;
      o.y = ao[mf][0][1] + bo4.y;
      o.z = ao[mf][0][2] + bo4.z;
      o.w = ao[mf][0][3] + bo4.w;
      *(float4*)&outF[(size_t)(m0 + mf * 16 + lrow) * 256 + s * 128 + w * 16 + quad * 4] = o;
    }
  }
}

extern "C" void kernel_launch(void* const* d_in, const int* in_sizes, int n_in,
                              void* d_out, int out_size, void* d_ws, size_t ws_size,
                              hipStream_t stream) {
  const float* x     = (const float*)d_in[0];
  const float* W_in  = (const float*)d_in[1];
  const float* b_in  = (const float*)d_in[2];
  const float* W_rec = (const float*)d_in[3];
  const float* b_rec = (const float*)d_in[4];
  const float* W_out = (const float*)d_in[5];
  const float* b_out = (const float*)d_in[6];
  const float* u_in  = (const float*)d_in[7];
  const float* u_rec = (const float*)d_in[8];
  const float* u_out = (const float*)d_in[9];

  const int B = 4096, H = 1024;

  char* w = (char*)d_ws;
  float* S = (float*)w;                               // 256 floats
  float* v = S + 256;                                 // 3 x 1024 floats
  unsigned short* WiT = (unsigned short*)(w + 16384); // 1M shorts (2 MB)
  unsigned short* WrT = WiT + (size_t)H * H;          // 1M shorts
  unsigned short* WoT = WrT + (size_t)H * H;          // 256K shorts
  unsigned short* xT  = WoT + (size_t)256 * H;        // 4M shorts (8 MB)
  unsigned short* himg = xT + (size_t)B * H;          // 128*2*32768 shorts (16 MB)
  unsigned* flags = (unsigned*)(himg + (size_t)128 * 2 * 32768);  // 256*64 B
  unsigned* xcds  = flags + 256 * 16;                 // 256 u32

  hipMemsetAsync(w, 0, 16384, stream);                // zero S, v
  hipMemsetAsync(flags, 0, 256 * 64 + 1024, stream);  // zero flags + xcds

  dim3 t256(256);
  spec_col3<<<dim3(4, 16, 3), t256, 0, stream>>>(W_in, W_rec, W_out, u_in, u_rec, u_out, v);
  reduce3<<<2307, t256, 0, stream>>>(W_in, W_rec, W_out, v, S);
  cvt_all<<<1024, t256, 0, stream>>>((const float4*)W_in, (const float4*)W_rec,
                                     (const float4*)W_out, (const float4*)x, S,
                                     (ushort4*)WiT, (ushort4*)WrT,
                                     (ushort4*)WoT, (ushort4*)xT);

  Mods mods;
  for (int t = 0; t < 32; ++t) mods.m[t] = (float)(1.0 + 0.1 * sin(0.3 * (double)t));
  {
    void* args[] = {(void*)&xT, (void*)&WiT, (void*)&WrT, (void*)&WoT,
                    (void*)&b_in, (void*)&b_rec, (void*)&b_out,
                    (void*)&himg, (void*)&flags, (void*)&xcds,
                    (void*)&d_out, (void*)&mods};
    hipLaunchCooperativeKernel((const void*)rnn_all, dim3(256), dim3(512),
                               args, 0, stream);
  }
}

// Round 15
// 602.449 us; speedup vs baseline: 1.1703x; 1.1703x over previous
//
#include <hip/hip_runtime.h>
#include <hip/hip_bf16.h>
#include <math.h>
#include <stdint.h>

// HolomorphicEqProp: B=4096, D_IN=H=1024, D_OUT=256, steps=30.
// Round-24: revert R22/R23's nt hints (both regressed: nt-store pushed h
// past L2, nt-load demoted lines the partner still needed -> critical-path
// MALL latency). Back to R21 (490us steady, best known) + two register-
// budgeted pipeline deepenings:
//  (a) PERSISTENT W ring: Wsrc is identical every step; the sweep's tail
//      wrap-loads ((ks+8)&31 -> kc 0..3) already leave the ring holding
//      next sweep's prologue. Keeping wring[4][NF] live across the t-loop
//      deletes the 16-load per-sweep W prologue and gives ring sets 0-3 a
//      ~2000cyc cross-step lead (epilogue+flag-wait+barrier) — absorbing
//      MALL misses on thrashed Wr lines.
//  (b) h ring 4->8 sets: post-barrier h reads (L2 ~200cyc) get ~280cyc
//      in-flight lead instead of ~160.
// VGPR: R21 measured 116; +32 (hf) lands ~150-190 << 256 cap @ 2 waves/
// SIMD. WRITE_SIZE is the spill tripwire (>300MB = abort).
// Everything else byte-identical to R21.

#define EPSF 1e-12f

typedef short bf16x8 __attribute__((ext_vector_type(8)));
typedef float f32x4 __attribute__((ext_vector_type(4)));

struct Mods { float m[32]; };

__device__ __forceinline__ unsigned short f2bf(float f) {
  union { float f; unsigned u; } v; v.f = f;
  unsigned r = v.u + 0x7FFFu + ((v.u >> 16) & 1u);  // RNE
  return (unsigned short)(r >> 16);
}

// packed f32x2 -> bf16x2 (RNE), single VALU op
__device__ __forceinline__ unsigned cvt_pk_bf16(float lo, float hi) {
  unsigned r;
  asm("v_cvt_pk_bf16_f32 %0, %1, %2" : "=v"(r) : "v"(lo), "v"(hi));
  return r;
}

// tanh(x) = 1 - 2/(exp(2x)+1). Saturates exactly; abs err ~1e-7 << bf16 eps.
__device__ __forceinline__ float tanh_fast(float x) {
  float e = __expf(2.0f * x);
  float r = __builtin_amdgcn_rcpf(e + 1.0f);
  return fmaf(-2.0f, r, 1.0f);
}

__device__ __forceinline__ float block_reduce_sum(float x) {
#pragma unroll
  for (int o = 32; o > 0; o >>= 1) x += __shfl_down(x, o, 64);
  __shared__ float sm[8];
  int lane = threadIdx.x & 63, w = threadIdx.x >> 6;
  if (lane == 0) sm[w] = x;
  __syncthreads();
  float t = 0.f;
  if (threadIdx.x == 0) {
    int nw = (int)(blockDim.x >> 6);
    for (int i = 0; i < nw; ++i) t += sm[i];
  }
  return t;
}

// ---------------- fused spectral-norm setup (fp32, exact) ----------------

__global__ void spec_col3(const float* __restrict__ Wi, const float* __restrict__ Wr,
                          const float* __restrict__ Wo, const float* __restrict__ ui,
                          const float* __restrict__ ur, const float* __restrict__ uo,
                          float* __restrict__ v) {
  int z = blockIdx.z;
  const float* W = (z == 0) ? Wi : (z == 1) ? Wr : Wo;
  const float* u = (z == 0) ? ui : (z == 1) ? ur : uo;
  int M = (z == 2) ? 256 : 1024;
  int i0 = blockIdx.y * 64;
  if (i0 >= M) return;
  int j = blockIdx.x * blockDim.x + threadIdx.x;
  float acc = 0.f;
  for (int i = i0; i < i0 + 64; ++i)
    acc += W[(size_t)i * 1024 + j] * u[i];
  atomicAdd(&v[z * 1024 + j], acc);
}

// Fused norm+rowsq (R19-validated): blocks 0..2303 rowsq, 2304..2306 norms.
__global__ void reduce3(const float* __restrict__ Wi, const float* __restrict__ Wr,
                        const float* __restrict__ Wo, const float* __restrict__ v,
                        float* __restrict__ S) {
  int bid = blockIdx.x;
  if (bid >= 2304) {
    int z = bid - 2304;
    float acc = 0.f;
    for (int i = threadIdx.x; i < 1024; i += blockDim.x) {
      float x = v[z * 1024 + i];
      acc += x * x;
    }
    float t = block_reduce_sum(acc);
    if (threadIdx.x == 0) S[z] = t;
    return;
  }
  int z = (bid < 1024) ? 0 : (bid < 2048) ? 1 : 2;
  int row = bid - ((z == 0) ? 0 : (z == 1) ? 1024 : 2048);
  const float* W = (z == 0) ? Wi : (z == 1) ? Wr : Wo;
  const float* vv = v + z * 1024;
  float acc = 0.f;
  for (int j = threadIdx.x; j < 1024; j += blockDim.x)
    acc += W[(size_t)row * 1024 + j] * vv[j];
  float r = block_reduce_sum(acc);
  if (threadIdx.x == 0) atomicAdd(&S[3 + z], r * r);
}

__device__ __forceinline__ ushort4 cvt4e(float4 w, float s) {
  ushort4 r;
  r.x = f2bf(w.x * s); r.y = f2bf(w.y * s); r.z = f2bf(w.z * s); r.w = f2bf(w.w * s);
  return r;
}

// sigma^-1 (exact spec_finalize math, inlined; R19-validated)
__device__ __forceinline__ float inv_sigma(float nvsq, float wv2) {
  float nv = sqrtf(nvsq);
  float inv = 1.f / (nv + EPSF);
  float u2sq = wv2 * inv * inv;
  float nu = sqrtf(u2sq);
  float sigma = u2sq / (nu + EPSF);
  return 1.f / sigma;
}

// Tiled-output conversion (R20-validated, byte-identical).
__global__ void cvt_all(const float4* __restrict__ Wi, const float4* __restrict__ Wr,
                        const float4* __restrict__ Wo, const float4* __restrict__ x,
                        const float* __restrict__ S,
                        ushort4* __restrict__ oWi, ushort4* __restrict__ oWr,
                        ushort4* __restrict__ oWo, ushort4* __restrict__ ox) {
  float s6 = inv_sigma(S[0], S[3]);
  float s7 = inv_sigma(S[1], S[4]);
  float s8 = inv_sigma(S[2], S[5]);
  int stride = gridDim.x * blockDim.x;
  int t0 = blockIdx.x * blockDim.x + threadIdx.x;
  for (int i = t0; i < 262144; i += stride) {  // Wi: 1024 rows
    int n = i >> 8, ku = i & 255;
    int kc = ku >> 3, quad = (ku >> 1) & 3, j4 = ku & 1;
    oWi[(((n >> 4) * 32 + kc) * 64 + (n & 15) + 16 * quad) * 2 + j4] = cvt4e(Wi[i], s6);
  }
  for (int i = t0; i < 262144; i += stride) {  // Wr: 1024 rows
    int n = i >> 8, ku = i & 255;
    int kc = ku >> 3, quad = (ku >> 1) & 3, j4 = ku & 1;
    oWr[(((n >> 4) * 32 + kc) * 64 + (n & 15) + 16 * quad) * 2 + j4] = cvt4e(Wr[i], s7);
  }
  for (int i = t0; i < 65536; i += stride) {   // Wo: 256 rows
    int n = i >> 8, ku = i & 255;
    int kc = ku >> 3, quad = (ku >> 1) & 3, j4 = ku & 1;
    oWo[(((n >> 4) * 32 + kc) * 64 + (n & 15) + 16 * quad) * 2 + j4] = cvt4e(Wo[i], s8);
  }
  for (int i = t0; i < 1048576; i += stride) { // x: 4096 rows, block-tiled
    int m = i >> 8, ku = i & 255;
    int kc = ku >> 3, quad = (ku >> 1) & 3, j4 = ku & 1;
    ox[(size_t)(m >> 5) * 8192 +
       ((((m >> 4) & 1) * 32 + kc) * 64 + (m & 15) + 16 * quad) * 2 + j4] =
        cvt4e(x[i], 1.0f);
  }
}

// ---------------- fused streaming RNN (pair-split, no LDS) ---------------

// K-sweep: B-operand h frags (2 mf, 8-set ring) from hsrc, A-operand W
// frags (NF, 4-set ring) from global tiled weights. FILLW: fill the W ring
// in the prologue (first use of a W slice); when false the caller's ring
// already holds kc 0..3 (maintained by the tail wrap-loads of the previous
// sweep over the SAME Wsrc). All ring indices compile-time (rule #20).
template <int NF, bool FILLW>
__device__ __forceinline__ void sweepT(const unsigned short* hsrc,
                                       const unsigned short* __restrict__ Wsrc,
                                       int lx, f32x4 acc[2][NF],
                                       bf16x8 wf[4][NF]) {
  bf16x8 hf[8][2];
#define LOADW(S, KC)                                                        \
  {                                                                         \
    int kq = (KC) & 31;                                                     \
    _Pragma("unroll")                                                       \
    for (int nf = 0; nf < NF; ++nf)                                         \
      wf[S][nf] = *(const bf16x8*)(Wsrc + (nf * 32 + kq) * 512 + lx);       \
  }
#define LOADH(S, KC)                                                        \
  {                                                                         \
    int kq = (KC) & 31;                                                     \
    hf[S][0] = *(const bf16x8*)(hsrc + kq * 512 + lx);                      \
    hf[S][1] = *(const bf16x8*)(hsrc + (32 + kq) * 512 + lx);               \
  }
  if (FILLW) { LOADW(0, 0) LOADW(1, 1) LOADW(2, 2) LOADW(3, 3) }
  LOADH(0, 0) LOADH(1, 1) LOADH(2, 2) LOADH(3, 3)
  LOADH(4, 4) LOADH(5, 5) LOADH(6, 6) LOADH(7, 7)
#pragma unroll 1
  for (int kc = 0; kc < 32; kc += 8) {
#define STEP(P)                                                             \
    {                                                                       \
      __builtin_amdgcn_s_setprio(1);                                        \
      _Pragma("unroll")                                                     \
      for (int nf = 0; nf < NF; ++nf) {                                     \
        acc[0][nf] = __builtin_amdgcn_mfma_f32_16x16x32_bf16(               \
            wf[(P) & 3][nf], hf[P][0], acc[0][nf], 0, 0, 0);                \
        acc[1][nf] = __builtin_amdgcn_mfma_f32_16x16x32_bf16(               \
            wf[(P) & 3][nf], hf[P][1], acc[1][nf], 0, 0, 0);                \
      }                                                                     \
      __builtin_amdgcn_s_setprio(0);                                        \
      LOADW((P) & 3, kc + (P) + 4)                                          \
      LOADH(P, kc + (P) + 8)                                                \
    }
    STEP(0) STEP(1) STEP(2) STEP(3) STEP(4) STEP(5) STEP(6) STEP(7)
#undef STEP
  }
#undef LOADW
#undef LOADH
}

// 256 blocks x 512 threads (8 waves = 2/SIMD). bid = s*128 + p:
// pair p (batch rows [p*32,+32)), half s (h-cols [s*512,+512)).
// Round-robin => XCD(bid) = bid&7 = p&7 for both halves (runtime-checked).
// h: global tiled images himg[p][parity] (64KB each; full 1024 cols,
// halves written disjointly by the two blocks). Wave w: cols
// [s*512 + w*64, +64) for recurrence, [s*128 + w*16, +16) for output.
__global__ __launch_bounds__(512, 2) void rnn_all(
    const unsigned short* __restrict__ xT,   // tiled x (per 32-row block)
    const unsigned short* __restrict__ WiT,  // tiled Wi (scaled bf16)
    const unsigned short* __restrict__ WrT,  // tiled Wr
    const unsigned short* __restrict__ WoT,  // tiled Wo
    const float* __restrict__ b_in,
    const float* __restrict__ b_rec,
    const float* __restrict__ b_out,
    unsigned short* __restrict__ himg,       // 128 pairs x 2 x 32768 shorts
    unsigned* __restrict__ flags,            // (p*2+s)*16 u32 stride (64B)
    unsigned* __restrict__ xcds,             // p*2+s
    float* __restrict__ outF,
    Mods mods) {
  const int tid = threadIdx.x;
  const int w = tid >> 6, lane = tid & 63;
  const int lrow = lane & 15, quad = lane >> 4;
  const int lx = lane * 8;
  const int bid = (int)blockIdx.x;
  const int p = bid & 127, s = bid >> 7;
  const int m0 = p * 32;
  const int nfbase = s * 32 + w * 4;        // Wr/Wi frag-row base for wave
  unsigned short* img0 = himg + (size_t)p * 65536;
  unsigned short* img1 = img0 + 32768;
  unsigned* myflag = flags + (size_t)(p * 2 + s) * 16;
  unsigned* ptflag = flags + (size_t)(p * 2 + (1 - s)) * 16;
  const unsigned short* xb = xT + (size_t)p * 32768;
  const unsigned short* WrSrc = WrT + (size_t)nfbase * 32 * 512;

  unsigned myxcc = 0;
  if (tid == 0) {
    asm volatile("s_getreg_b32 %0, hwreg(HW_REG_XCC_ID)" : "=s"(myxcc));
    // RELEASE: xcd publish drained before any later flag is observable.
    __hip_atomic_store(xcds + (p * 2 + s), myxcc, __ATOMIC_RELEASE,
                       __HIP_MEMORY_SCOPE_AGENT);
  }

  // per-lane biases for this wave's 64 recurrence cols
  float4 brec4[4];
#pragma unroll
  for (int nf = 0; nf < 4; ++nf)
    brec4[nf] = *(const float4*)&b_rec[s * 512 + w * 64 + nf * 16 + quad * 4];

  // ---- xproj: xpr[mf][nf] = (x @ Wi^T + b_in) for own 512 cols ----
  f32x4 xpr[2][4];
  {
    bf16x8 wx[4][4];
    f32x4 xa[2][4] = {};
    sweepT<4, true>(xb, WiT + (size_t)nfbase * 32 * 512, lx, xa, wx);
#pragma unroll
    for (int nf = 0; nf < 4; ++nf) {
      float4 bin4 = *(const float4*)&b_in[s * 512 + w * 64 + nf * 16 + quad * 4];
#pragma unroll
      for (int mf = 0; mf < 2; ++mf) {
        xpr[mf][nf][0] = xa[mf][nf][0] + bin4.x;
        xpr[mf][nf][1] = xa[mf][nf][1] + bin4.y;
        xpr[mf][nf][2] = xa[mf][nf][2] + bin4.z;
        xpr[mf][nf][3] = xa[mf][nf][3] + bin4.w;
      }
    }
  }

  // ---- persistent Wr ring: fill once; every sweep's tail wrap-loads
  // re-fill slots 0..3 with kc 0..3 of the SAME slice (cross-step lead).
  bf16x8 wring[4][4];
#pragma unroll
  for (int S = 0; S < 4; ++S)
#pragma unroll
    for (int nf = 0; nf < 4; ++nf)
      wring[S][nf] = *(const bf16x8*)(WrSrc + (nf * 32 + S) * 512 + lx);

  int fastv = 1;  // meaningful in tid0 only; decided at t==1

  // ---- t = 0..29: compute h(t) into img[t&1] (own kc range) ----
#pragma unroll 1
  for (int t = 0; t < 30; ++t) {
    f32x4 acc[2][4] = {};
    if (t) {
      if (tid == 0) {
        while (__hip_atomic_load(ptflag, __ATOMIC_RELAXED,
                                 __HIP_MEMORY_SCOPE_AGENT) < (unsigned)t)
          __builtin_amdgcn_s_sleep(2);
        if (t == 1) {
          unsigned px = __hip_atomic_load(xcds + (p * 2 + (1 - s)),
                                          __ATOMIC_RELAXED, __HIP_MEMORY_SCOPE_AGENT);
          fastv = ((px & 15u) == (myxcc & 15u)) ? 1 : 0;
        }
        if (fastv) {
          asm volatile("buffer_inv sc0" ::: "memory");  // L1 only; h in XCD L2
        } else {
          (void)__hip_atomic_load(ptflag, __ATOMIC_ACQUIRE, __HIP_MEMORY_SCOPE_AGENT);
        }
      }
      __syncthreads();  // partner h(t-1) visible to all waves
      sweepT<4, false>((t & 1) ? img0 : img1, WrSrc, lx, acc, wring);
    }
    const float mod = mods.m[t];
    unsigned short* dst = (t & 1) ? img1 : img0;
#pragma unroll
    for (int nf = 0; nf < 4; ++nf) {
      // write own h as next step's B-frag (R20-validated mapping, kc
      // rebased to the pair image): ncol = s*512 + w*64 + nf*16 + quad*4+r
      const int kcp = s * 16 + w * 2 + (nf >> 1);
      const int lanep = lrow + 16 * (((nf & 1) * 2 + (quad >> 1)));
#pragma unroll
      for (int mf = 0; mf < 2; ++mf) {
        float h0 = tanh_fast(fmaf(acc[mf][nf][0] + brec4[nf].x, mod, xpr[mf][nf][0]));
        float h1 = tanh_fast(fmaf(acc[mf][nf][1] + brec4[nf].y, mod, xpr[mf][nf][1]));
        float h2 = tanh_fast(fmaf(acc[mf][nf][2] + brec4[nf].z, mod, xpr[mf][nf][2]));
        float h3 = tanh_fast(fmaf(acc[mf][nf][3] + brec4[nf].w, mod, xpr[mf][nf][3]));
        uint2 pk = {cvt_pk_bf16(h0, h1), cvt_pk_bf16(h2, h3)};
        *(uint2*)(dst + (mf * 32 + kcp) * 512 + lanep * 8 + (quad & 1) * 4) = pk;
      }
    }
    __syncthreads();  // all waves' h(t) stores drained to XCD L2
    if (tid == 0) {
      if (t == 0 || !fastv)  // t=0: release also orders the xcd publish path
        __hip_atomic_store(myflag, (unsigned)(t + 1), __ATOMIC_RELEASE,
                           __HIP_MEMORY_SCOPE_AGENT);
      else
        __hip_atomic_store(myflag, (unsigned)(t + 1), __ATOMIC_RELAXED,
                           __HIP_MEMORY_SCOPE_AGENT);
    }
  }

  // ---- fused output GEMM: out = h29 @ Wo^T + b_out (h29 = parity 1) ----
  if (tid == 0) {
    while (__hip_atomic_load(ptflag, __ATOMIC_RELAXED,
                             __HIP_MEMORY_SCOPE_AGENT) < 30u)
      __builtin_amdgcn_s_sleep(2);
    if (fastv) {
      asm volatile("buffer_inv sc0" ::: "memory");
    } else {
      (void)__hip_atomic_load(ptflag, __ATOMIC_ACQUIRE, __HIP_MEMORY_SCOPE_AGENT);
    }
  }
  __syncthreads();
  {
    bf16x8 wo[4][1];
    f32x4 ao[2][1] = {};
    sweepT<1, true>(img1, WoT + (size_t)((s * 8 + w) * 32) * 512, lx, ao, wo);
    float4 bo4 = *(const float4*)&b_out[s * 128 + w * 16 + quad * 4];
#pragma unroll
    for (int mf = 0; mf < 2; ++mf) {
      float4 o;
      o.x = ao[mf][0][0] + bo4.x;
      o.y = ao[mf][0][1] + bo4.y;
      o.z = ao[mf][0][2] + bo4.z;
      o.w = ao[mf][0][3] + bo4.w;
      *(float4*)&outF[(size_t)(m0 + mf * 16 + lrow) * 256 + s * 128 + w * 16 + quad * 4] = o;
    }
  }
}

extern "C" void kernel_launch(void* const* d_in, const int* in_sizes, int n_in,
                              void* d_out, int out_size, void* d_ws, size_t ws_size,
                              hipStream_t stream) {
  const float* x     = (const float*)d_in[0];
  const float* W_in  = (const float*)d_in[1];
  const float* b_in  = (const float*)d_in[2];
  const float* W_rec = (const float*)d_in[3];
  const float* b_rec = (const float*)d_in[4];
  const float* W_out = (const float*)d_in[5];
  const float* b_out = (const float*)d_in[6];
  const float* u_in  = (const float*)d_in[7];
  const float* u_rec = (const float*)d_in[8];
  const float* u_out = (const float*)d_in[9];

  const int B = 4096, H = 1024;

  char* w = (char*)d_ws;
  float* S = (float*)w;                               // 256 floats
  float* v = S + 256;                                 // 3 x 1024 floats
  unsigned short* WiT = (unsigned short*)(w + 16384); // 1M shorts (2 MB)
  unsigned short* WrT = WiT + (size_t)H * H;          // 1M shorts
  unsigned short* WoT = WrT + (size_t)H * H;          // 256K shorts
  unsigned short* xT  = WoT + (size_t)256 * H;        // 4M shorts (8 MB)
  unsigned short* himg = xT + (size_t)B * H;          // 128*2*32768 shorts (16 MB)
  unsigned* flags = (unsigned*)(himg + (size_t)128 * 2 * 32768);  // 256*64 B
  unsigned* xcds  = flags + 256 * 16;                 // 256 u32

  hipMemsetAsync(w, 0, 16384, stream);                // zero S, v
  hipMemsetAsync(flags, 0, 256 * 64 + 1024, stream);  // zero flags + xcds

  dim3 t256(256);
  spec_col3<<<dim3(4, 16, 3), t256, 0, stream>>>(W_in, W_rec, W_out, u_in, u_rec, u_out, v);
  reduce3<<<2307, t256, 0, stream>>>(W_in, W_rec, W_out, v, S);
  cvt_all<<<1024, t256, 0, stream>>>((const float4*)W_in, (const float4*)W_rec,
                                     (const float4*)W_out, (const float4*)x, S,
                                     (ushort4*)WiT, (ushort4*)WrT,
                                     (ushort4*)WoT, (ushort4*)xT);

  Mods mods;
  for (int t = 0; t < 32; ++t) mods.m[t] = (float)(1.0 + 0.1 * sin(0.3 * (double)t));
  {
    void* args[] = {(void*)&xT, (void*)&WiT, (void*)&WrT, (void*)&WoT,
                    (void*)&b_in, (void*)&b_rec, (void*)&b_out,
                    (void*)&himg, (void*)&flags, (void*)&xcds,
                    (void*)&d_out, (void*)&mods};
    hipLaunchCooperativeKernel((const void*)rnn_all, dim3(256), dim3(512),
                               args, 0, stream);
  }
}